// Round 1
// baseline (1063.557 us; speedup 1.0000x reference)
//
#include <hip/hip_runtime.h>
#include <math.h>

#define NN 20000   // nodes
#define NE 40000   // edges
#define H 64
#define F_ATOM 62
#define F_BOND 6
#define NB 512     // graphs

__device__ __forceinline__ float selu_f(float x) {
    const float scale = 1.0507009873554805f;
    const float alpha = 1.6732632423543772f;
    return scale * (x > 0.0f ? x : alpha * (__expf(x) - 1.0f));
}

// h[n][c] = c < F_ATOM ? nf[n][c] : 0
__global__ void pad_h_kernel(const float* __restrict__ nf, float* __restrict__ h) {
    int idx = blockIdx.x * blockDim.x + threadIdx.x;
    if (idx >= NN * H) return;
    int n = idx >> 6, c = idx & 63;
    h[idx] = (c < F_ATOM) ? nf[n * F_ATOM + c] : 0.0f;
}

// mlp[e][i] = relu(ef[e] @ Wm + bm)
__global__ void edge_mlp_kernel(const float* __restrict__ ef, const float* __restrict__ Wm,
                                const float* __restrict__ bm, float* __restrict__ mlp) {
    int t = blockIdx.x * blockDim.x + threadIdx.x;
    if (t >= NE * H) return;
    int e = t >> 6, i = t & 63;
    const float* efe = ef + e * F_BOND;
    float s = bm[i];
#pragma unroll
    for (int j = 0; j < F_BOND; ++j) s = fmaf(efe[j], Wm[j * H + i], s);
    mlp[t] = fmaxf(s, 0.0f);
}

// em[e,i] = sum_k mlp[e,k] * sum_j Ew[k, i*64+j] * h[er[e], j];  atomicAdd into msg[ed[e], i]
// 64 edges / block; 4 waves; wave w handles edges [w*16, w*16+16), lane = output col i.
__global__ __launch_bounds__(256) void edge_message_kernel(
    const float* __restrict__ h, const float* __restrict__ mlp,
    const int* __restrict__ ed, const int* __restrict__ er,
    const float* __restrict__ Ew, float* __restrict__ msg) {
    __shared__ float hj_s[64][68];
    __shared__ float mlp_s[64][68];
    __shared__ int eidx_s[64];
    __shared__ int edom_s[64];
    const int t = threadIdx.x;
    const int eb = blockIdx.x * 64;
    if (t < 64) { eidx_s[t] = er[eb + t]; edom_s[t] = ed[eb + t]; }
    __syncthreads();
#pragma unroll
    for (int it = 0; it < 4; ++it) {
        int idx4 = t + it * 256;              // 0..1023 ; e = idx4/16, c4 = idx4%16
        int e = idx4 >> 4, c4 = idx4 & 15;
        float4 hv = *reinterpret_cast<const float4*>(&h[eidx_s[e] * H + c4 * 4]);
        *reinterpret_cast<float4*>(&hj_s[e][c4 * 4]) = hv;
        float4 mv = *reinterpret_cast<const float4*>(&mlp[(eb + e) * H + c4 * 4]);
        *reinterpret_cast<float4*>(&mlp_s[e][c4 * 4]) = mv;
    }
    __syncthreads();
    const int i = t & 63;
    const int e0 = (t >> 6) * 16;
    float acc[16];
#pragma unroll
    for (int e = 0; e < 16; ++e) acc[e] = 0.0f;
    const float4* Ew4 = reinterpret_cast<const float4*>(Ew);
    for (int kc = 0; kc < 16; ++kc) {
        float mreg[64];
#pragma unroll
        for (int e = 0; e < 16; ++e)
#pragma unroll
            for (int k = 0; k < 4; ++k)
                mreg[e * 4 + k] = mlp_s[e0 + e][kc * 4 + k];
#pragma unroll 2
        for (int j4 = 0; j4 < 16; ++j4) {
            float4 h4[16];
#pragma unroll
            for (int e = 0; e < 16; ++e)
                h4[e] = *reinterpret_cast<const float4*>(&hj_s[e0 + e][j4 * 4]);
#pragma unroll
            for (int k = 0; k < 4; ++k) {
                float4 w = Ew4[(kc * 4 + k) * 1024 + i * 16 + j4];
#pragma unroll
                for (int e = 0; e < 16; ++e) {
                    float d = w.x * h4[e].x + w.y * h4[e].y + w.z * h4[e].z + w.w * h4[e].w;
                    acc[e] = fmaf(mreg[e * 4 + k], d, acc[e]);
                }
            }
        }
    }
#pragma unroll
    for (int e = 0; e < 16; ++e)
        atomicAdd(&msg[edom_s[e0 + e] * H + i], acc[e]);
}

// h[n,i] = selu(msg[n] @ Wu + bu[i] + h[n,i])   (4 nodes / block)
__global__ void node_update_kernel(const float* __restrict__ msg, const float* __restrict__ Wu,
                                   const float* __restrict__ bu, float* __restrict__ h) {
    __shared__ float ms[4][68];
    int t = threadIdx.x;
    int nb = blockIdx.x * 4;
    int ln = t >> 6, i = t & 63;
    ms[ln][i] = msg[(nb + ln) * H + i];
    __syncthreads();
    float s = bu[i];
#pragma unroll
    for (int k = 0; k < H; ++k) s = fmaf(ms[ln][k], Wu[k * H + i], s);
    int o = (nb + ln) * H + i;
    h[o] = selu_f(s + h[o]);
}

// ae[n,i] = h[n] @ Wae + bae[i]
__global__ void atom_embed_kernel(const float* __restrict__ h, const float* __restrict__ Wae,
                                  const float* __restrict__ bae, float* __restrict__ ae) {
    __shared__ float hs[4][68];
    int t = threadIdx.x;
    int nb = blockIdx.x * 4;
    int ln = t >> 6, i = t & 63;
    hs[ln][i] = h[(nb + ln) * H + i];
    __syncthreads();
    float s = bae[i];
#pragma unroll
    for (int k = 0; k < H; ++k) s = fmaf(hs[ln][k], Wae[k * H + i], s);
    ae[(nb + ln) * H + i] = s;
}

// aa = selu(ae @ WR + bR); atomicAdd into gsum[gid[n]]
__global__ void readout_kernel(const float* __restrict__ ae, const float* __restrict__ WR,
                               const float* __restrict__ bR, const int* __restrict__ gid,
                               float* __restrict__ gsum) {
    __shared__ float as[4][68];
    int t = threadIdx.x;
    int nb = blockIdx.x * 4;
    int ln = t >> 6, i = t & 63;
    as[ln][i] = ae[(nb + ln) * H + i];
    __syncthreads();
    float s = bR[i];
#pragma unroll
    for (int k = 0; k < H; ++k) s = fmaf(as[ln][k], WR[k * H + i], s);
    atomicAdd(&gsum[gid[nb + ln] * H + i], selu_f(s));
}

// per graph: ge = tanh(gsum); mo = relu(ge @ Wmlp + bmlp); out = mo @ Wout + bout
__global__ void final_kernel(const float* __restrict__ gsum, const float* __restrict__ Wmlp,
                             const float* __restrict__ bmlp, const float* __restrict__ Wout,
                             const float* __restrict__ bout, float* __restrict__ out) {
    __shared__ float ge[64];
    int g = blockIdx.x, i = threadIdx.x;
    ge[i] = tanhf(gsum[g * H + i]);
    __syncthreads();
    float s = bmlp[i];
#pragma unroll
    for (int k = 0; k < H; ++k) s = fmaf(ge[k], Wmlp[k * H + i], s);
    float mo = fmaxf(s, 0.0f) * Wout[i];
#pragma unroll
    for (int off = 32; off > 0; off >>= 1) mo += __shfl_down(mo, off);
    if (i == 0) out[g] = mo + bout[0];
}

extern "C" void kernel_launch(void* const* d_in, const int* in_sizes, int n_in,
                              void* d_out, int out_size, void* d_ws, size_t ws_size,
                              hipStream_t stream) {
    const float* nf   = (const float*)d_in[0];
    const float* ef   = (const float*)d_in[1];
    const int*   ed   = (const int*)d_in[2];   // edge_domain (scatter dest)
    const int*   er   = (const int*)d_in[3];   // edge_range  (gather src)
    const int*   gid  = (const int*)d_in[4];
    const float* Wm   = (const float*)d_in[5];
    const float* bm   = (const float*)d_in[6];
    const float* Ew   = (const float*)d_in[7];
    const float* Wu0  = (const float*)d_in[8];
    const float* bu0  = (const float*)d_in[9];
    const float* Wu1  = (const float*)d_in[10];
    const float* bu1  = (const float*)d_in[11];
    const float* Wae  = (const float*)d_in[12];
    const float* bae  = (const float*)d_in[13];
    const float* WR   = (const float*)d_in[14];
    const float* bR   = (const float*)d_in[15];
    const float* Wmlp = (const float*)d_in[16];
    const float* bmlp = (const float*)d_in[17];
    const float* Wout = (const float*)d_in[18];
    const float* bout = (const float*)d_in[19];
    float* out = (float*)d_out;

    float* ws   = (float*)d_ws;
    float* h    = ws;                                   // 20000*64
    float* mlp  = ws + 1280000;                         // 40000*64
    float* msg  = ws + 1280000 + 2560000;               // 20000*64 (also reused as ae)
    float* gsum = msg + 1280000;                        // 512*64

    pad_h_kernel<<<(NN * H + 255) / 256, 256, 0, stream>>>(nf, h);
    edge_mlp_kernel<<<(NE * H + 255) / 256, 256, 0, stream>>>(ef, Wm, bm, mlp);

    for (int stepi = 0; stepi < 2; ++stepi) {
        hipMemsetAsync(msg, 0, NN * H * sizeof(float), stream);
        edge_message_kernel<<<NE / 64, 256, 0, stream>>>(h, mlp, ed, er, Ew, msg);
        node_update_kernel<<<NN / 4, 256, 0, stream>>>(msg, stepi ? Wu1 : Wu0,
                                                       stepi ? bu1 : bu0, h);
    }

    atom_embed_kernel<<<NN / 4, 256, 0, stream>>>(h, Wae, bae, msg);  // msg reused as ae
    hipMemsetAsync(gsum, 0, NB * H * sizeof(float), stream);
    readout_kernel<<<NN / 4, 256, 0, stream>>>(msg, WR, bR, gid, gsum);
    final_kernel<<<NB, 64, 0, stream>>>(gsum, Wmlp, bmlp, Wout, bout, out);
}

// Round 2
// 164.863 us; speedup vs baseline: 6.4512x; 6.4512x over previous
//
#include <hip/hip_runtime.h>
#include <math.h>

#define NN 20000   // nodes
#define NE 40000   // edges
#define H 64
#define F_ATOM 62
#define F_BOND 6
#define NB 512     // graphs

typedef __bf16 bf16x8 __attribute__((ext_vector_type(8)));
typedef float f32x16 __attribute__((ext_vector_type(16)));

__device__ __forceinline__ float selu_f(float x) {
    const float scale = 1.0507009873554805f;
    const float alpha = 1.6732632423543772f;
    return scale * (x > 0.0f ? x : alpha * (__expf(x) - 1.0f));
}

// h[n][c] = c < F_ATOM ? nf[n][c] : 0
__global__ void pad_h_kernel(const float* __restrict__ nf, float* __restrict__ h) {
    int idx = blockIdx.x * blockDim.x + threadIdx.x;
    if (idx >= NN * H) return;
    int n = idx >> 6, c = idx & 63;
    h[idx] = (c < F_ATOM) ? nf[n * F_ATOM + c] : 0.0f;
}

// mlp[e][i] = relu(ef[e] @ Wm + bm)
__global__ void edge_mlp_kernel(const float* __restrict__ ef, const float* __restrict__ Wm,
                                const float* __restrict__ bm, float* __restrict__ mlp) {
    int t = blockIdx.x * blockDim.x + threadIdx.x;
    if (t >= NE * H) return;
    int e = t >> 6, i = t & 63;
    const float* efe = ef + e * F_BOND;
    float s = bm[i];
#pragma unroll
    for (int j = 0; j < F_BOND; ++j) s = fmaf(efe[j], Wm[j * H + i], s);
    mlp[t] = fmaxf(s, 0.0f);
}

// Pre-convert Ew (f32 [64][4096]) into bf16 B-fragment-linear order for
// mfma_f32_32x32x16_bf16:  out[((c*2+nt)*64 + l)*8 + t] =
//   bf16( Ew[kk][i*64 + j] ),  kk=c>>2, j=(c&3)*16+(l>>5)*8+t, i=nt*32+(l&31)
__global__ void ew_prep_kernel(const float* __restrict__ Ew, __bf16* __restrict__ out) {
    int tid = blockIdx.x * 256 + threadIdx.x;      // 0..32767
    int l = tid & 63;
    int nt = (tid >> 6) & 1;
    int c = tid >> 7;                              // 0..255
    int kk = c >> 2;
    int jbase = (c & 3) * 16 + (l >> 5) * 8;
    int i = nt * 32 + (l & 31);
    const float* src = Ew + kk * 4096 + i * 64 + jbase;
    __bf16* dst = out + tid * 8;
#pragma unroll
    for (int t = 0; t < 8; ++t) dst[t] = (__bf16)src[t];
}

// em[e,i] = sum_{kk,j} mlp[e,kk]*hj[e,j]*Ew[kk,i*64+j]; atomicAdd into msg[ed[e]]
// Block: 128 threads (2 waves), 64 edges. Wave w owns edges [w*32, w*32+32),
// M=32 x N=64 x K=4096 via mfma_f32_32x32x16_bf16; A built on the fly.
__global__ __launch_bounds__(128) void edge_message_mfma(
    const float* __restrict__ h, const float* __restrict__ mlp,
    const int* __restrict__ ed, const int* __restrict__ er,
    const __bf16* __restrict__ ewb, float* __restrict__ msg)
{
    __shared__ float mlpT_s[64][65];      // [kk][e_local], pad 65 -> conflict-free reads
    __shared__ bf16x8 ewbuf[2][1024];     // double-buffered Ew slice (8 chunks x 2 ntiles x 64 lanes)
    __shared__ int edom_s[64];

    const int t = threadIdx.x;
    const int w = t >> 6;
    const int lane = t & 63;
    const int l31 = lane & 31;
    const int hf = lane >> 5;
    const int eb = blockIdx.x * 64;

    if (t < 64) edom_s[t] = ed[eb + t];

    // stage mlp transposed into LDS (64 edges x 64 kk)
#pragma unroll
    for (int r = 0; r < 8; ++r) {
        int lin = r * 128 + t;            // 0..1023 float4 units
        int e = lin >> 4;                 // 0..63
        int k0 = (lin & 15) * 4;
        float4 v = *reinterpret_cast<const float4*>(mlp + (eb + e) * H + k0);
        mlpT_s[k0 + 0][e] = v.x;
        mlpT_s[k0 + 1][e] = v.y;
        mlpT_s[k0 + 2][e] = v.z;
        mlpT_s[k0 + 3][e] = v.w;
    }

    // preload this lane's hj values: e = w*32 + (lane&31), j = q*16 + (lane>>5)*8 + tt
    const int eloc = w * 32 + l31;
    const int hrow = er[eb + eloc];
    float hjr[32];
    {
        const float* hp = h + hrow * H + hf * 8;
#pragma unroll
        for (int q = 0; q < 4; ++q) {
            float4 v0 = *reinterpret_cast<const float4*>(hp + q * 16);
            float4 v1 = *reinterpret_cast<const float4*>(hp + q * 16 + 4);
            hjr[q * 8 + 0] = v0.x; hjr[q * 8 + 1] = v0.y;
            hjr[q * 8 + 2] = v0.z; hjr[q * 8 + 3] = v0.w;
            hjr[q * 8 + 4] = v1.x; hjr[q * 8 + 5] = v1.y;
            hjr[q * 8 + 6] = v1.z; hjr[q * 8 + 7] = v1.w;
        }
    }

    // async-stage one 16 KB Ew slice (8 K-chunks) into LDS buffer `buf`
    auto stage = [&](int s, int buf) {
        const __bf16* gs = ewb + s * 8192 + w * 4096 + lane * 8;
        char* lb = reinterpret_cast<char*>(&ewbuf[buf][0]) + w * 8192 + lane * 16;
#pragma unroll
        for (int r = 0; r < 8; ++r) {
            __builtin_amdgcn_global_load_lds(
                (const __attribute__((address_space(1))) void*)(gs + r * 512),
                (__attribute__((address_space(3))) void*)(lb + r * 1024),
                16, 0, 0);
        }
    };

    f32x16 acc0, acc1;
#pragma unroll
    for (int i = 0; i < 16; ++i) { acc0[i] = 0.0f; acc1[i] = 0.0f; }

    stage(0, 0);
    asm volatile("s_waitcnt vmcnt(0)" ::: "memory");
    __syncthreads();

    int cur = 0;
    for (int s = 0; s < 32; ++s) {
        if (s < 31) stage(s + 1, cur ^ 1);
        const int e0 = w * 32;
#pragma unroll
        for (int cc = 0; cc < 8; ++cc) {
            const int kk = s * 2 + (cc >> 2);
            const int q = cc & 3;
            float mval = mlpT_s[kk][e0 + l31];
            bf16x8 a;
#pragma unroll
            for (int tt = 0; tt < 8; ++tt) a[tt] = (__bf16)(mval * hjr[q * 8 + tt]);
            bf16x8 b0 = ewbuf[cur][(cc * 2 + 0) * 64 + lane];
            bf16x8 b1 = ewbuf[cur][(cc * 2 + 1) * 64 + lane];
            acc0 = __builtin_amdgcn_mfma_f32_32x32x16_bf16(a, b0, acc0, 0, 0, 0);
            acc1 = __builtin_amdgcn_mfma_f32_32x32x16_bf16(a, b1, acc1, 0, 0, 0);
        }
        asm volatile("s_waitcnt vmcnt(0)" ::: "memory");
        __syncthreads();
        cur ^= 1;
    }

    // C/D layout (verified): col = lane&31, row = (r&3) + 8*(r>>2) + 4*(lane>>5)
#pragma unroll
    for (int r = 0; r < 16; ++r) {
        const int m = (r & 3) + 8 * (r >> 2) + 4 * hf;
        const int dom = edom_s[w * 32 + m];
        atomicAdd(&msg[dom * H + l31], acc0[r]);
        atomicAdd(&msg[dom * H + 32 + l31], acc1[r]);
    }
}

// h[n,i] = selu(msg[n] @ Wu + bu[i] + h[n,i])   (4 nodes / block)
__global__ void node_update_kernel(const float* __restrict__ msg, const float* __restrict__ Wu,
                                   const float* __restrict__ bu, float* __restrict__ h) {
    __shared__ float ms[4][68];
    int t = threadIdx.x;
    int nb = blockIdx.x * 4;
    int ln = t >> 6, i = t & 63;
    ms[ln][i] = msg[(nb + ln) * H + i];
    __syncthreads();
    float s = bu[i];
#pragma unroll
    for (int k = 0; k < H; ++k) s = fmaf(ms[ln][k], Wu[k * H + i], s);
    int o = (nb + ln) * H + i;
    h[o] = selu_f(s + h[o]);
}

// ae[n,i] = h[n] @ Wae + bae[i]
__global__ void atom_embed_kernel(const float* __restrict__ h, const float* __restrict__ Wae,
                                  const float* __restrict__ bae, float* __restrict__ ae) {
    __shared__ float hs[4][68];
    int t = threadIdx.x;
    int nb = blockIdx.x * 4;
    int ln = t >> 6, i = t & 63;
    hs[ln][i] = h[(nb + ln) * H + i];
    __syncthreads();
    float s = bae[i];
#pragma unroll
    for (int k = 0; k < H; ++k) s = fmaf(hs[ln][k], Wae[k * H + i], s);
    ae[(nb + ln) * H + i] = s;
}

// aa = selu(ae @ WR + bR); atomicAdd into gsum[gid[n]]
__global__ void readout_kernel(const float* __restrict__ ae, const float* __restrict__ WR,
                               const float* __restrict__ bR, const int* __restrict__ gid,
                               float* __restrict__ gsum) {
    __shared__ float as[4][68];
    int t = threadIdx.x;
    int nb = blockIdx.x * 4;
    int ln = t >> 6, i = t & 63;
    as[ln][i] = ae[(nb + ln) * H + i];
    __syncthreads();
    float s = bR[i];
#pragma unroll
    for (int k = 0; k < H; ++k) s = fmaf(as[ln][k], WR[k * H + i], s);
    atomicAdd(&gsum[gid[nb + ln] * H + i], selu_f(s));
}

// per graph: ge = tanh(gsum); mo = relu(ge @ Wmlp + bmlp); out = mo @ Wout + bout
__global__ void final_kernel(const float* __restrict__ gsum, const float* __restrict__ Wmlp,
                             const float* __restrict__ bmlp, const float* __restrict__ Wout,
                             const float* __restrict__ bout, float* __restrict__ out) {
    __shared__ float ge[64];
    int g = blockIdx.x, i = threadIdx.x;
    ge[i] = tanhf(gsum[g * H + i]);
    __syncthreads();
    float s = bmlp[i];
#pragma unroll
    for (int k = 0; k < H; ++k) s = fmaf(ge[k], Wmlp[k * H + i], s);
    float mo = fmaxf(s, 0.0f) * Wout[i];
#pragma unroll
    for (int off = 32; off > 0; off >>= 1) mo += __shfl_down(mo, off);
    if (i == 0) out[g] = mo + bout[0];
}

extern "C" void kernel_launch(void* const* d_in, const int* in_sizes, int n_in,
                              void* d_out, int out_size, void* d_ws, size_t ws_size,
                              hipStream_t stream) {
    const float* nf   = (const float*)d_in[0];
    const float* ef   = (const float*)d_in[1];
    const int*   ed   = (const int*)d_in[2];   // edge_domain (scatter dest)
    const int*   er   = (const int*)d_in[3];   // edge_range  (gather src)
    const int*   gid  = (const int*)d_in[4];
    const float* Wm   = (const float*)d_in[5];
    const float* bm   = (const float*)d_in[6];
    const float* Ew   = (const float*)d_in[7];
    const float* Wu0  = (const float*)d_in[8];
    const float* bu0  = (const float*)d_in[9];
    const float* Wu1  = (const float*)d_in[10];
    const float* bu1  = (const float*)d_in[11];
    const float* Wae  = (const float*)d_in[12];
    const float* bae  = (const float*)d_in[13];
    const float* WR   = (const float*)d_in[14];
    const float* bR   = (const float*)d_in[15];
    const float* Wmlp = (const float*)d_in[16];
    const float* bmlp = (const float*)d_in[17];
    const float* Wout = (const float*)d_in[18];
    const float* bout = (const float*)d_in[19];
    float* out = (float*)d_out;

    float* ws   = (float*)d_ws;
    float* h    = ws;                                   // 20000*64
    float* mlp  = ws + 1280000;                         // 40000*64
    float* msg  = ws + 1280000 + 2560000;               // 20000*64 (reused as ae)
    float* gsum = msg + 1280000;                        // 512*64
    __bf16* ewb = (__bf16*)(gsum + 32768);              // 262144 bf16 = 512 KB

    pad_h_kernel<<<(NN * H + 255) / 256, 256, 0, stream>>>(nf, h);
    edge_mlp_kernel<<<(NE * H + 255) / 256, 256, 0, stream>>>(ef, Wm, bm, mlp);
    ew_prep_kernel<<<128, 256, 0, stream>>>(Ew, ewb);

    for (int stepi = 0; stepi < 2; ++stepi) {
        hipMemsetAsync(msg, 0, NN * H * sizeof(float), stream);
        edge_message_mfma<<<NE / 64, 128, 0, stream>>>(h, mlp, ed, er, ewb, msg);
        node_update_kernel<<<NN / 4, 256, 0, stream>>>(msg, stepi ? Wu1 : Wu0,
                                                       stepi ? bu1 : bu0, h);
    }

    atom_embed_kernel<<<NN / 4, 256, 0, stream>>>(h, Wae, bae, msg);  // msg reused as ae
    hipMemsetAsync(gsum, 0, NB * H * sizeof(float), stream);
    readout_kernel<<<NN / 4, 256, 0, stream>>>(msg, WR, bR, gid, gsum);
    final_kernel<<<NB, 64, 0, stream>>>(gsum, Wmlp, bmlp, Wout, bout, out);
}